// Round 11
// baseline (525.331 us; speedup 1.0000x reference)
//
#include <hip/hip_runtime.h>
#include <hip/hip_bf16.h>
#include <math.h>

// ---------------------------------------------------------------------------
// Mamba2 block forward. bf16 storage + MFMA everywhere, fp32 accumulate.
// b=4, L=4096, D_MODEL=1024, D_INNER=2048, D_STATE=128, N_HEADS=32, HEAD_DIM=64
//
// Memory plan (234,455,040 B <= proven-safe 234.6 MB) + sc_raw in dead xpre
// tail. R11: GEMM = 256x256 8-phase with K-half-split half-tiles:
//   LDS L[2][4][256*32] (A_k0,A_k1,B_k0,B_k1 per buf, 128 KiB total).
//   Phase order (fh0,k0)(fh1,k0)(fh0,k1)(fh1,k1); kh0 regions dead after
//   ph2, kh1 after ph4 -> stage 1.5 tiles ahead with 1-phase kill gap:
//   ph1->T+1.A1, ph2->T+1.B1, ph3->T+2.A0, ph4->T+2.B0. vmcnt(10) at
//   ph1/ph3 retires exactly the half-tiles those phases read (staged 5-6
//   phases earlier). B-fragments register-held across the fh pair.
// ---------------------------------------------------------------------------

#define BL    16384
#define NCONV 2304
#define LDXP  2336

typedef __hip_bfloat16 bf16;
typedef __attribute__((ext_vector_type(8))) short bf16x8_i;
typedef __attribute__((ext_vector_type(4))) float f32x4;

union BF8 { uint4 u; bf16 h[8]; };
union BF2 { uint u; bf16 h[2]; };

__device__ __forceinline__ void gload_lds16(const void* g, void* l) {
  __builtin_amdgcn_global_load_lds(
      (__attribute__((address_space(1))) void*)(uintptr_t)g,
      (__attribute__((address_space(3))) void*)(uint32_t)(uintptr_t)l,
      16, 0, 0);
}

// ---------------- bf16 MFMA GEMM, 256x256 8-phase:  C = A @ B^T ------------
template<typename TC, bool CLAMPB>
__global__ __launch_bounds__(512) void gemm_bt_256(
    const bf16* __restrict__ A, int lda,
    const bf16* __restrict__ B, int ldb,
    TC* __restrict__ C, int ldc, int N, int K)
{
  // regions: 0=A_k0, 1=A_k1, 2=B_k0, 3=B_k1; each 256 rows x 32 k (16 KB)
  __shared__ __align__(16) bf16 L[2][4][8192];
  const int tid  = threadIdx.x;
  const int lane = tid & 63;
  const int wid  = tid >> 6;
  const int wm   = wid >> 2;          // M-half (0..1): rows wm*128..+127
  const int wn   = wid & 3;           // N quarter: cols wn*64..+63

  // XCD-chunked bijective swizzle (requires nwg % 8 == 0)
  const int gx  = gridDim.x;
  const int nwg = gx * gridDim.y;
  const int q   = nwg >> 3;
  int id = blockIdx.y * gx + blockIdx.x;
  id = (id & 7) * q + (id >> 3);
  const int bm = (id / gx) * 256;
  const int bn = (id % gx) * 256;

  f32x4 acc[8][4] = {};               // [fh*4+mf][nf]

  // per-lane ds_read offsets within a region (swizzle: blk ^= (row>>1)&3)
  int aofs[2][4], bofs[4];
  #pragma unroll
  for (int fh = 0; fh < 2; ++fh)
    #pragma unroll
    for (int mf = 0; mf < 4; ++mf) {
      const int ar = wm * 128 + fh * 64 + mf * 16 + (lane & 15);
      aofs[fh][mf] = ar * 32 + (((lane >> 4) ^ ((ar >> 1) & 3)) << 3);
    }
  #pragma unroll
  for (int nf = 0; nf < 4; ++nf) {
    const int br = wn * 64 + nf * 16 + (lane & 15);
    bofs[nf] = br * 32 + (((lane >> 4) ^ ((br >> 1) & 3)) << 3);
  }

  const int NT = K >> 6;
  // staging: thread t covers row (t>>2) (+128 on 2nd issue), src col-block
  // (t&3)^((row>>1)&3) -> linear LDS dest holds the swizzled layout.
  const int srow = tid >> 2;
  const int sblk = tid & 3;

  auto stageA = [&](int tile, int kh) {
    const int kt = min(tile, NT - 1);
    const int k0 = kt * 64 + kh * 32;
    bf16* dst = &L[tile & 1][kh][0];
    #pragma unroll
    for (int i = 0; i < 2; ++i) {
      const int r = i * 128 + srow;
      const int blk = sblk ^ ((r >> 1) & 3);
      gload_lds16(A + (size_t)(bm + r) * lda + k0 + blk * 8,
                  dst + i * 4096 + wid * 512);
    }
  };
  auto stageB = [&](int tile, int kh) {
    const int kt = min(tile, NT - 1);
    const int k0 = kt * 64 + kh * 32;
    bf16* dst = &L[tile & 1][2 + kh][0];
    #pragma unroll
    for (int i = 0; i < 2; ++i) {
      const int r = i * 128 + srow;
      const int blk = sblk ^ ((r >> 1) & 3);
      int grow = bn + r;
      if (CLAMPB) grow = min(grow, N - 1);
      gload_lds16(B + (size_t)grow * ldb + k0 + blk * 8,
                  dst + i * 4096 + wid * 512);
    }
  };

  // prologue: t0 all 4 + t1.A0, t1.B0  (oldest->newest for vmcnt math)
  stageA(0, 0); stageB(0, 0); stageA(0, 1); stageB(0, 1);
  stageA(1, 0); stageB(1, 0);

  for (int T = 0; T < NT; ++T) {
    const int buf = T & 1;
    const bf16* A0r = &L[buf][0][0];
    const bf16* A1r = &L[buf][1][0];
    const bf16* B0r = &L[buf][2][0];
    const bf16* B1r = &L[buf][3][0];
    bf16x8_i bfr[4], af[4];

    // ---- ph1 (fh0, kh0): stage T+1.A1; wait T.{A0,B0}
    stageA(T + 1, 1);
    asm volatile("s_waitcnt vmcnt(10)" ::: "memory");
    __builtin_amdgcn_sched_barrier(0);
    __builtin_amdgcn_s_barrier();
    #pragma unroll
    for (int mf = 0; mf < 4; ++mf) af[mf] = *(const bf16x8_i*)(A0r + aofs[0][mf]);
    #pragma unroll
    for (int nf = 0; nf < 4; ++nf) bfr[nf] = *(const bf16x8_i*)(B0r + bofs[nf]);
    asm volatile("s_waitcnt lgkmcnt(0)" ::: "memory");
    __builtin_amdgcn_sched_barrier(0);
    __builtin_amdgcn_s_setprio(1);
    #pragma unroll
    for (int mf = 0; mf < 4; ++mf)
      #pragma unroll
      for (int nf = 0; nf < 4; ++nf)
        acc[mf][nf] = __builtin_amdgcn_mfma_f32_16x16x32_bf16(
            af[mf], bfr[nf], acc[mf][nf], 0, 0, 0);
    __builtin_amdgcn_s_setprio(0);
    __builtin_amdgcn_s_barrier();

    // ---- ph2 (fh1, kh0): stage T+1.B1; B-frags reused from ph1
    stageB(T + 1, 1);
    #pragma unroll
    for (int mf = 0; mf < 4; ++mf) af[mf] = *(const bf16x8_i*)(A0r + aofs[1][mf]);
    asm volatile("s_waitcnt lgkmcnt(0)" ::: "memory");
    __builtin_amdgcn_sched_barrier(0);
    __builtin_amdgcn_s_setprio(1);
    #pragma unroll
    for (int mf = 0; mf < 4; ++mf)
      #pragma unroll
      for (int nf = 0; nf < 4; ++nf)
        acc[4 + mf][nf] = __builtin_amdgcn_mfma_f32_16x16x32_bf16(
            af[mf], bfr[nf], acc[4 + mf][nf], 0, 0, 0);
    __builtin_amdgcn_s_setprio(0);
    __builtin_amdgcn_s_barrier();

    // ---- ph3 (fh0, kh1): stage T+2.A0 (buf.A0 dead since ph2); wait T.{A1,B1}
    stageA(T + 2, 0);
    asm volatile("s_waitcnt vmcnt(10)" ::: "memory");
    __builtin_amdgcn_sched_barrier(0);
    __builtin_amdgcn_s_barrier();
    #pragma unroll
    for (int mf = 0; mf < 4; ++mf) af[mf] = *(const bf16x8_i*)(A1r + aofs[0][mf]);
    #pragma unroll
    for (int nf = 0; nf < 4; ++nf) bfr[nf] = *(const bf16x8_i*)(B1r + bofs[nf]);
    asm volatile("s_waitcnt lgkmcnt(0)" ::: "memory");
    __builtin_amdgcn_sched_barrier(0);
    __builtin_amdgcn_s_setprio(1);
    #pragma unroll
    for (int mf = 0; mf < 4; ++mf)
      #pragma unroll
      for (int nf = 0; nf < 4; ++nf)
        acc[mf][nf] = __builtin_amdgcn_mfma_f32_16x16x32_bf16(
            af[mf], bfr[nf], acc[mf][nf], 0, 0, 0);
    __builtin_amdgcn_s_setprio(0);
    __builtin_amdgcn_s_barrier();

    // ---- ph4 (fh1, kh1): stage T+2.B0 (buf.B0 dead since ph2)
    stageB(T + 2, 0);
    #pragma unroll
    for (int mf = 0; mf < 4; ++mf) af[mf] = *(const bf16x8_i*)(A1r + aofs[1][mf]);
    asm volatile("s_waitcnt lgkmcnt(0)" ::: "memory");
    __builtin_amdgcn_sched_barrier(0);
    __builtin_amdgcn_s_setprio(1);
    #pragma unroll
    for (int mf = 0; mf < 4; ++mf)
      #pragma unroll
      for (int nf = 0; nf < 4; ++nf)
        acc[4 + mf][nf] = __builtin_amdgcn_mfma_f32_16x16x32_bf16(
            af[mf], bfr[nf], acc[4 + mf][nf], 0, 0, 0);
    __builtin_amdgcn_s_setprio(0);
    __builtin_amdgcn_s_barrier();
  }

  // epilogue: per-wave 128x64 at (bm + wm*128, bn + wn*64)
  const int cr = (lane >> 4) * 4;
  const int cc = lane & 15;
  #pragma unroll
  for (int fh = 0; fh < 2; ++fh)
    #pragma unroll
    for (int mf = 0; mf < 4; ++mf) {
      #pragma unroll
      for (int nf = 0; nf < 4; ++nf) {
        const int n = bn + wn * 64 + nf * 16 + cc;
        if (n < N) {
          #pragma unroll
          for (int r = 0; r < 4; ++r) {
            const int m = bm + wm * 128 + fh * 64 + mf * 16 + cr + r;
            if constexpr (sizeof(TC) == 2)
              ((bf16*)C)[(size_t)m * ldc + n] =
                  __float2bfloat16(acc[fh * 4 + mf][nf][r]);
            else
              ((float*)C)[(size_t)m * ldc + n] = acc[fh * 4 + mf][nf][r];
          }
        }
      }
    }
}

// ---------------- conversion -----------------------------------------------
__global__ __launch_bounds__(256) void cvt_f32_bf16(
    const float* __restrict__ in, bf16* __restrict__ out)
{
  const size_t i = (size_t)(blockIdx.x * 256 + threadIdx.x) * 8;
  float4 a = *(const float4*)(in + i);
  float4 b = *(const float4*)(in + i + 4);
  BF8 o;
  o.h[0] = __float2bfloat16(a.x); o.h[1] = __float2bfloat16(a.y);
  o.h[2] = __float2bfloat16(a.z); o.h[3] = __float2bfloat16(a.w);
  o.h[4] = __float2bfloat16(b.x); o.h[5] = __float2bfloat16(b.y);
  o.h[6] = __float2bfloat16(b.z); o.h[7] = __float2bfloat16(b.w);
  *(uint4*)(out + i) = o.u;
}

// ---------------- dt softplus + per-chunk Atot -----------------------------
__global__ __launch_bounds__(256) void dtsp_atot_kernel(
    const bf16* __restrict__ xpre, const float* __restrict__ dt_bias,
    const float* __restrict__ A_log,
    float* __restrict__ dtT, float* __restrict__ Atot)
{
  const int c = blockIdx.x, b = blockIdx.y;
  const int tid = threadIdx.x;
  const int h = tid & 31, lg = tid >> 5;
  __shared__ float red[8][33];
  float s = 0.f, vals[8];
  const bf16* src = xpre + ((size_t)b * 4096 + c * 64 + lg * 8) * LDXP + 2304 + h;
  const float bias = dt_bias[h];
  #pragma unroll
  for (int k = 0; k < 8; ++k) {
    float v = __bfloat162float(src[(size_t)k * LDXP]) + bias;
    v = fmaxf(v, 0.f) + log1pf(expf(-fabsf(v)));
    vals[k] = v; s += v;
  }
  float* dp = dtT + ((size_t)(b * 32 + h)) * 4096 + c * 64 + lg * 8;
  #pragma unroll
  for (int k = 0; k < 8; ++k) dp[k] = vals[k];
  red[lg][h] = s;
  __syncthreads();
  if (tid < 32) {
    float t = 0.f;
    #pragma unroll
    for (int g = 0; g < 8; ++g) t += red[g][tid];
    Atot[((size_t)b * 64 + c) * 32 + tid] = -expf(A_log[tid]) * t;
  }
}

// ---------------- depthwise causal conv(4) + bias + silu -------------------
__global__ __launch_bounds__(256) void conv_silu_kernel(
    const bf16* __restrict__ xpre,
    const float* __restrict__ conv_w,
    const float* __restrict__ conv_b,
    bf16* __restrict__ xBC)
{
  const int ch = blockIdx.x * 256 + threadIdx.x;  // < 2304
  const int t0 = blockIdx.y * 8;
  const int bb = blockIdx.z;
  const float w0 = conv_w[ch*4+0], w1 = conv_w[ch*4+1];
  const float w2 = conv_w[ch*4+2], w3 = conv_w[ch*4+3];
  const float bias = conv_b[ch];
  const size_t rb = (size_t)bb * 4096;
  const bf16* src = xpre + ch;
  float v0 = (t0 >= 3) ? __bfloat162float(src[(rb + t0 - 3) * LDXP]) : 0.f;
  float v1 = (t0 >= 2) ? __bfloat162float(src[(rb + t0 - 2) * LDXP]) : 0.f;
  float v2 = (t0 >= 1) ? __bfloat162float(src[(rb + t0 - 1) * LDXP]) : 0.f;
  for (int t = t0; t < t0 + 8; ++t) {
    float v3 = __bfloat162float(src[(rb + t) * LDXP]);
    float o = bias + w0*v0 + w1*v1 + w2*v2 + w3*v3;
    o = o / (1.f + expf(-o));
    xBC[(rb + t) * NCONV + ch] = __float2bfloat16(o);
    v0 = v1; v1 = v2; v2 = v3;
  }
}

// swizzle helper: XOR the 8-block index of l by low bits of the row
__device__ __forceinline__ int swz8(int row) { return ((row >> 3) & 7) << 3; }

// ---------------- S0: head-invariant raw scores  sc_raw = C.B^T ------------
__global__ __launch_bounds__(256) void s0_scores(
    const bf16* __restrict__ xBC, float* __restrict__ sc_raw)
{
  const int c = blockIdx.x, b = blockIdx.y;
  const int tid = threadIdx.x, lane = tid & 63, wid = tid >> 6;
  __shared__ bf16 Bc[64 * 136];
  __shared__ bf16 Cc[64 * 136];
  const size_t r0 = (size_t)b * 4096 + (size_t)c * 64;
  #pragma unroll
  for (int k = 0; k < 4; ++k) {
    int id = tid + k * 256, l = id >> 4, n0 = (id & 15) * 8;
    *(uint4*)(Bc + l * 136 + n0) =
        *(const uint4*)(xBC + (r0 + l) * NCONV + 2048 + n0);
    *(uint4*)(Cc + l * 136 + n0) =
        *(const uint4*)(xBC + (r0 + l) * NCONV + 2176 + n0);
  }
  __syncthreads();
  const int wr  = (wid & 1) * 32;   // l
  const int wcs = (wid >> 1) * 32;  // s
  f32x4 as[2][2] = {};
  #pragma unroll
  for (int ks = 0; ks < 4; ++ks) {
    const int k0 = ks * 32 + (lane >> 4) * 8;
    bf16x8_i af[2], bfr[2];
    #pragma unroll
    for (int i = 0; i < 2; ++i)
      af[i] = *(const bf16x8_i*)(Cc + (wr + i * 16 + (lane & 15)) * 136 + k0);
    #pragma unroll
    for (int j = 0; j < 2; ++j)
      bfr[j] = *(const bf16x8_i*)(Bc + (wcs + j * 16 + (lane & 15)) * 136 + k0);
    #pragma unroll
    for (int i = 0; i < 2; ++i)
      #pragma unroll
      for (int j = 0; j < 2; ++j)
        as[i][j] = __builtin_amdgcn_mfma_f32_16x16x32_bf16(
            af[i], bfr[j], as[i][j], 0, 0, 0);
  }
  float* dst = sc_raw + ((size_t)(b * 64 + c)) * 4096;
  const int cr = (lane >> 4) * 4, cc = lane & 15;
  #pragma unroll
  for (int i = 0; i < 2; ++i)
    #pragma unroll
    for (int r = 0; r < 4; ++r) {
      const int l = wr + i * 16 + cr + r;
      #pragma unroll
      for (int j = 0; j < 2; ++j)
        dst[l * 64 + wcs + j * 16 + cc] = as[i][j][r];
    }
}

// ---------------- S1: chunk-local states via MFMA --------------------------
__global__ __launch_bounds__(256) void s1_localstate(
    const bf16* __restrict__ xBC, const float* __restrict__ dtT,
    const float* __restrict__ A_log, bf16* __restrict__ states, int b)
{
  const int hh = blockIdx.x, c = blockIdx.y;
  const int tid = threadIdx.x, lane = tid & 63, wid = tid >> 6;
  __shared__ bf16 BT[128 * 72];    // [n][l^swz]
  __shared__ bf16 xwT[64 * 72];    // [p][l^swz]
  __shared__ bf16 Sout[64 * 136];  // bounce for coalesced store
  const size_t r0 = (size_t)b * 4096 + (size_t)c * 64;

  BF8 regB[4], regx[2];
  #pragma unroll
  for (int k = 0; k < 4; ++k) {
    int id = tid + k * 256, l = id >> 4, n0 = (id & 15) * 8;
    regB[k].u = *(const uint4*)(xBC + (r0 + l) * NCONV + 2048 + n0);
  }
  #pragma unroll
  for (int k = 0; k < 2; ++k) {
    int id = tid + k * 256, l = id >> 3, p0 = (id & 7) * 8;
    regx[k].u = *(const uint4*)(xBC + (r0 + l) * NCONV + hh * 64 + p0);
  }

  float d = dtT[((size_t)(b * 32 + hh)) * 4096 + c * 64 + lane];
  float Ah = -expf(A_log[hh]);
  float v = Ah * d;
  #pragma unroll
  for (int off = 1; off < 64; off <<= 1) {
    float up = __shfl_up(v, off, 64);
    if (lane >= off) v += up;
  }
  const float At = __shfl(v, 63, 64);
  const float w = d * __expf(At - v);

  #pragma unroll
  for (int k = 0; k < 4; ++k) {
    int id = tid + k * 256, l = id >> 4, n0 = (id & 15) * 8;
    #pragma unroll
    for (int j = 0; j < 8; ++j) {
      int n = n0 + j;
      BT[n * 72 + (l ^ swz8(n))] = regB[k].h[j];
    }
  }
  #pragma unroll
  for (int k = 0; k < 2; ++k) {
    int id = tid + k * 256, l = id >> 3, p0 = (id & 7) * 8;
    float wv = __shfl(w, l, 64);
    #pragma unroll
    for (int j = 0; j < 8; ++j) {
      int p = p0 + j;
      xwT[p * 72 + (l ^ swz8(p))] =
          __float2bfloat16(__bfloat162float(regx[k].h[j]) * wv);
    }
  }
  __syncthreads();

  const int wr = (wid & 1) * 32;   // p
  const int wc = (wid >> 1) * 64;  // n
  f32x4 acc[2][4] = {};
  #pragma unroll
  for (int ks = 0; ks < 2; ++ks) {
    const int k0 = ks * 32 + (lane >> 4) * 8;
    bf16x8_i a[2], bb[4];
    #pragma unroll
    for (int i = 0; i < 2; ++i) {
      int p = wr + i * 16 + (lane & 15);
      a[i] = *(const bf16x8_i*)(xwT + p * 72 + (k0 ^ swz8(p)));
    }
    #pragma unroll
    for (int j = 0; j < 4; ++j) {
      int n = wc + j * 16 + (lane & 15);
      bb[j] = *(const bf16x8_i*)(BT + n * 72 + (k0 ^ swz8(n)));
    }
    #pragma unroll
    for (int i = 0; i < 2; ++i)
      #pragma unroll
      for (int j = 0; j < 4; ++j)
        acc[i][j] = __builtin_amdgcn_mfma_f32_16x16x32_bf16(
            a[i], bb[j], acc[i][j], 0, 0, 0);
  }

  const int cr = (lane >> 4) * 4, cn = lane & 15;
  #pragma unroll
  for (int i = 0; i < 2; ++i)
    #pragma unroll
    for (int j = 0; j < 4; ++j)
      #pragma unroll
      for (int r = 0; r < 4; ++r)
        Sout[(wr + i * 16 + cr + r) * 136 + (wc + j * 16 + cn)] =
            __float2bfloat16(acc[i][j][r]);
  __syncthreads();
  bf16* sb = states + ((size_t)c * 32 + hh) * 8192;
  #pragma unroll
  for (int k = 0; k < 4; ++k) {
    int id = tid + k * 256, p = id >> 4, n0 = (id & 15) * 8;
    *(uint4*)(sb + p * 128 + n0) = *(const uint4*)(Sout + p * 136 + n0);
  }
}

// ---------------- S2: in-place scan over chunks (4-deep pipelined) ---------
__global__ __launch_bounds__(256) void s2_scan(
    bf16* __restrict__ states, const float* __restrict__ Atot, int b)
{
  const int h  = blockIdx.x >> 4;
  const int p  = ((blockIdx.x & 15) << 2) | (threadIdx.x >> 6);
  const int n0 = (threadIdx.x & 63) * 2;
  __shared__ float ec[64];
  if (threadIdx.x < 64)
    ec[threadIdx.x] = expf(Atot[((size_t)b * 64 + threadIdx.x) * 32 + h]);
  __syncthreads();
  bf16* ptr = states + ((size_t)h * 64 + p) * 128 + n0;
  const size_t cs = (size_t)32 * 8192;
  float ca = 0.f, cb = 0.f;
  BF2 g0, g1, g2, g3, q0, q1, q2, q3;
  g0.u = *(const uint*)(ptr + 0 * cs);
  g1.u = *(const uint*)(ptr + 1 * cs);
  g2.u = *(const uint*)(ptr + 2 * cs);
  g3.u = *(const uint*)(ptr + 3 * cs);
  for (int g = 0; g < 16; ++g) {
    const int c0 = g * 4;
    if (g < 15) {
      q0.u = *(const uint*)(ptr + (c0 + 4) * cs);
      q1.u = *(const uint*)(ptr + (c0 + 5) * cs);
      q2.u = *(const uint*)(ptr + (c0 + 6) * cs);
      q3.u = *(const uint*)(ptr + (c0 + 7) * cs);
    }
    BF2 o0, o1, o2, o3;
    const float e0 = ec[c0], e1 = ec[c0+1], e2 = ec[c0+2], e3 = ec[c0+3];
    o0.h[0] = __float2bfloat16(ca); o0.h[1] = __float2bfloat16(cb);
    ca = fmaf(e0, ca, __bfloat162float(g0.h[0]));
    cb = fmaf(e0, cb, __bfloat162float(g0.h[1]));
    o1.h[0] = __float2bfloat16(ca); o1.h[1] = __float2bfloat16(cb);
    ca = fmaf(e1, ca, __bfloat162float(g1.h[0]));
    cb = fmaf(e1, cb, __bfloat162float(g1.h[1]));
    o2.h[0] = __float2bfloat16(ca); o2.h[1] = __float2bfloat16(cb);
    ca = fmaf(e2, ca, __bfloat162float(g2.h[0]));
    cb = fmaf(e2, cb, __bfloat162float(g2.h[1]));
    o3.h[0] = __float2bfloat16(ca); o3.h[1] = __float2bfloat16(cb);
    ca = fmaf(e3, ca, __bfloat162float(g3.h[0]));
    cb = fmaf(e3, cb, __bfloat162float(g3.h[1]));
    *(uint*)(ptr + (c0 + 0) * cs) = o0.u;
    *(uint*)(ptr + (c0 + 1) * cs) = o1.u;
    *(uint*)(ptr + (c0 + 2) * cs) = o2.u;
    *(uint*)(ptr + (c0 + 3) * cs) = o3.u;
    g0 = q0; g1 = q1; g2 = q2; g3 = q3;
  }
}

// ---------------- S3: chunk outputs via MFMA (scores precomputed) ----------
__global__ __launch_bounds__(256) void s3_output(
    const bf16* __restrict__ xBC, const float* __restrict__ dtT,
    const float* __restrict__ A_log, const float* __restrict__ Dp,
    const bf16* __restrict__ states, const float* __restrict__ sc_raw,
    bf16* __restrict__ Y, int b)
{
  const int hh = blockIdx.x, c = blockIdx.y;
  const int tid = threadIdx.x, lane = tid & 63, wid = tid >> 6;
  __shared__ bf16 Cc[64 * 136];   // [l][n]
  __shared__ bf16 Yb[64 * 136];   // output bounce
  __shared__ bf16 Sin[64 * 136];  // [p][n]
  __shared__ bf16 xT[64 * 72];    // [p][l^swz]
  __shared__ bf16 scb[64 * 72];   // [l][s] post-decay scores
  __shared__ float Ac[64], dts[64];
  const size_t r0 = (size_t)b * 4096 + (size_t)c * 64;

  if (tid < 64) {
    float d = dtT[((size_t)(b * 32 + hh)) * 4096 + c * 64 + tid];
    float Ah = -expf(A_log[hh]);
    float v = Ah * d;
    #pragma unroll
    for (int off = 1; off < 64; off <<= 1) {
      float up = __shfl_up(v, off, 64);
      if (tid >= off) v += up;
    }
    Ac[tid] = v; dts[tid] = d;
  }

  #pragma unroll
  for (int k = 0; k < 4; ++k) {
    int id = tid + k * 256, l = id >> 4, n0 = (id & 15) * 8;
    *(uint4*)(Cc + l * 136 + n0) =
        *(const uint4*)(xBC + (r0 + l) * NCONV + 2176 + n0);
  }
  const bf16* sb = states + ((size_t)c * 32 + hh) * 8192;
  #pragma unroll
  for (int k = 0; k < 4; ++k) {
    int id = tid + k * 256, p = id >> 4, n0 = (id & 15) * 8;
    *(uint4*)(Sin + p * 136 + n0) = *(const uint4*)(sb + p * 128 + n0);
  }
  #pragma unroll
  for (int k = 0; k < 2; ++k) {
    int id = tid + k * 256, l = id >> 3, p0 = (id & 7) * 8;
    BF8 v; v.u = *(const uint4*)(xBC + (r0 + l) * NCONV + hh * 64 + p0);
    #pragma unroll
    for (int j = 0; j < 8; ++j) {
      int p = p0 + j;
      xT[p * 72 + (l ^ swz8(p))] = v.h[j];
    }
  }
  __syncthreads();

  const int wr  = (wid & 1) * 32;   // l
  const int wcs = (wid >> 1) * 32;  // s / p
  bf16x8_i afrag[2][4];
  #pragma unroll
  for (int ks = 0; ks < 4; ++ks) {
    const int k0 = ks * 32 + (lane >> 4) * 8;
    #pragma unroll
    for (int i = 0; i < 2; ++i)
      afrag[i][ks] =
          *(const bf16x8_i*)(Cc + (wr + i * 16 + (lane & 15)) * 136 + k0);
  }
  {
    const float* scr = sc_raw + ((size_t)(b * 64 + c)) * 4096;
    #pragma unroll
    for (int k = 0; k < 4; ++k) {
      int idx = tid + k * 256;            // < 1024
      int l = idx >> 4, s0 = (idx & 15) * 4;
      float4 v = *(const float4*)(scr + l * 64 + s0);
      const float acl = Ac[l];
      float vv[4] = {v.x, v.y, v.z, v.w};
      #pragma unroll
      for (int j = 0; j < 4; ++j) {
        int s = s0 + j;
        float val = (s <= l) ? vv[j] * __expf(acl - Ac[s]) * dts[s] : 0.f;
        scb[l * 72 + s] = __float2bfloat16(val);
      }
    }
  }
  __syncthreads();

  f32x4 ay[2][2] = {};
  #pragma unroll
  for (int ks = 0; ks < 4; ++ks) {
    const int k0 = ks * 32 + (lane >> 4) * 8;
    #pragma unroll
    for (int j = 0; j < 2; ++j) {
      bf16x8_i bfr =
          *(const bf16x8_i*)(Sin + (wcs + j * 16 + (lane & 15)) * 136 + k0);
      #pragma unroll
      for (int i = 0; i < 2; ++i)
        ay[i][j] = __builtin_amdgcn_mfma_f32_16x16x32_bf16(
            afrag[i][ks], bfr, ay[i][j], 0, 0, 0);
    }
  }
  const int cr = (lane >> 4) * 4, cc = lane & 15;
  #pragma unroll
  for (int i = 0; i < 2; ++i)
    #pragma unroll
    for (int r = 0; r < 4; ++r) {
      const float dk = __expf(Ac[wr + i * 16 + cr + r]);
      #pragma unroll
      for (int j = 0; j < 2; ++j) ay[i][j][r] *= dk;
    }
  #pragma unroll
  for (int ks = 0; ks < 2; ++ks) {
    const int k0 = ks * 32 + (lane >> 4) * 8;
    bf16x8_i a2[2], b2[2];
    #pragma unroll
    for (int i = 0; i < 2; ++i)
      a2[i] = *(const bf16x8_i*)(scb + (wr + i * 16 + (lane & 15)) * 72 + k0);
    #pragma unroll
    for (int j = 0; j < 2; ++j) {
      int p = wcs + j * 16 + (lane & 15);
      b2[j] = *(const bf16x8_i*)(xT + p * 72 + (k0 ^ swz8(p)));
    }
    #pragma unroll
    for (int i = 0; i < 2; ++i)
      #pragma unroll
      for (int j = 0; j < 2; ++j)
        ay[i][j] = __builtin_amdgcn_mfma_f32_16x16x32_bf16(
            a2[i], b2[j], ay[i][j], 0, 0, 0);
  }
  const float Dh = Dp[hh];
  #pragma unroll
  for (int i = 0; i < 2; ++i)
    #pragma unroll
    for (int r = 0; r < 4; ++r) {
      const int l = wr + i * 16 + cr + r;
      #pragma unroll
      for (int j = 0; j < 2; ++j) {
        const int p = wcs + j * 16 + cc;
        float xv = __bfloat162float(xT[p * 72 + (l ^ swz8(p))]);
        Yb[l * 136 + p] = __float2bfloat16(ay[i][j][r] + Dh * xv);
      }
    }
  __syncthreads();
  #pragma unroll
  for (int k = 0; k < 2; ++k) {
    int id = tid + k * 256, l = id >> 3, p0 = (id & 7) * 8;
    *(uint4*)(Y + (r0 + l) * 2048 + hh * 64 + p0) =
        *(const uint4*)(Yb + l * 136 + p0);
  }
}

// ---------------- t = rmsnorm(y * silu(z)) * norm_w  (in place over y) -----
__global__ __launch_bounds__(256) void gate_rmsnorm_kernel(
    bf16* __restrict__ y, const bf16* __restrict__ z,
    const float* __restrict__ norm_w)
{
  const size_t row = blockIdx.x;
  const int tid = threadIdx.x;
  __shared__ float red[4];
  const bf16* zr = z + row * 2048;
  bf16* yr = y + row * 2048;
  BF8 zv, yv;
  zv.u = *(const uint4*)(zr + tid * 8);
  yv.u = *(const uint4*)(yr + tid * 8);
  float t[8];
  float local = 0.f;
  #pragma unroll
  for (int j = 0; j < 8; ++j) {
    float zz = __bfloat162float(zv.h[j]);
    float yy = __bfloat162float(yv.h[j]);
    float tv = yy * (zz / (1.f + expf(-zz)));
    t[j] = tv;
    local += tv * tv;
  }
  #pragma unroll
  for (int off = 32; off; off >>= 1) local += __shfl_down(local, off, 64);
  if ((tid & 63) == 0) red[tid >> 6] = local;
  __syncthreads();
  const float total = red[0] + red[1] + red[2] + red[3];
  const float scale = rsqrtf(total * (1.f / 2048.f) + 1e-5f);
  BF8 o;
  #pragma unroll
  for (int j = 0; j < 8; ++j)
    o.h[j] = __float2bfloat16(t[j] * scale * norm_w[tid * 8 + j]);
  *(uint4*)(yr + tid * 8) = o.u;
}

// ---------------------------------------------------------------------------
extern "C" void kernel_launch(void* const* d_in, const int* in_sizes, int n_in,
                              void* d_out, int out_size, void* d_ws, size_t ws_size,
                              hipStream_t stream) {
  (void)in_sizes; (void)n_in; (void)out_size; (void)ws_size;
  const float* u          = (const float*)d_in[0];
  const float* in_proj_w  = (const float*)d_in[1];
  const float* conv_w     = (const float*)d_in[2];
  const float* conv_b     = (const float*)d_in[3];
  const float* dt_bias    = (const float*)d_in[4];
  const float* A_log      = (const float*)d_in[5];
  const float* Dp         = (const float*)d_in[6];
  const float* norm_w     = (const float*)d_in[7];
  const float* out_proj_w = (const float*)d_in[8];
  float* out = (float*)d_out;

  char* ws = (char*)d_ws;
  bf16*  u_bf   = (bf16*)ws;                           //  33,554,432
  bf16*  xpre   = (bf16*)(ws + 33554432);              //  76,546,048
  bf16*  xBCc   = (bf16*)(ws + 110100480);             //  75,497,472
  float* dtT    = (float*)(ws + 185597952);            //   2,097,152
  bf16*  W_xpre = (bf16*)(ws + 187695104);             //   4,784,128
  bf16*  W_z    = (bf16*)(ws + 192479232);             //   4,194,304
  bf16*  w_out  = (bf16*)(ws + 196673536);             //   4,194,304
  float* Atot   = (float*)(ws + 200867840);            //      32,768
  bf16*  states = (bf16*)(ws + 200900608);             //  33,554,432
  bf16*  ybuf   = xpre;                                // y ld 2048 (post-SSD)
  bf16*  zbuf   = xBCc;                                // z ld 2048 (post-SSD)
  float* sc_raw = (float*)(ws + 100663296);            // 4 MB in xpre tail

  // 0) conversions
  cvt_f32_bf16<<<dim3(8192), 256, 0, stream>>>(u, u_bf);
  cvt_f32_bf16<<<dim3(1168), 256, 0, stream>>>(in_proj_w + (size_t)2048*1024,
                                               W_xpre);   // 2336x1024
  cvt_f32_bf16<<<dim3(1024), 256, 0, stream>>>(in_proj_w, W_z);
  cvt_f32_bf16<<<dim3(1024), 256, 0, stream>>>(out_proj_w, w_out);
  // 1) GEMM-X: xpre = u_bf @ W_xpre^T  (N=2336, clamp B rows)
  gemm_bt_256<bf16, true><<<dim3(10, 64), 512, 0, stream>>>(
      u_bf, 1024, W_xpre, 1024, xpre, LDXP, 2336, 1024);
  // 2) dt softplus + Atot
  dtsp_atot_kernel<<<dim3(64, 4), 256, 0, stream>>>(xpre, dt_bias, A_log,
                                                    dtT, Atot);
  // 3) conv + silu
  conv_silu_kernel<<<dim3(9, 512, 4), 256, 0, stream>>>(xpre, conv_w, conv_b,
                                                        xBCc);
  // 3b) head-invariant raw scores, all batches (xpre tail now dead)
  s0_scores<<<dim3(64, 4), 256, 0, stream>>>(xBCc, sc_raw);
  // 4) SSD, one batch at a time (states buffer holds one batch)
  for (int b = 0; b < 4; ++b) {
    s1_localstate<<<dim3(32, 64), 256, 0, stream>>>(xBCc, dtT, A_log,
                                                    states, b);
    s2_scan<<<dim3(512), 256, 0, stream>>>(states, Atot, b);
    s3_output<<<dim3(32, 64), 256, 0, stream>>>(xBCc, dtT, A_log, Dp,
                                                states, sc_raw, ybuf, b);
  }
  // 5) GEMM-Z: z = u_bf @ W_z^T (over dead conv buffer)
  gemm_bt_256<bf16, false><<<dim3(8, 64), 512, 0, stream>>>(
      u_bf, 1024, W_z, 1024, zbuf, 2048, 2048, 1024);
  // 6) gate + rmsnorm (t over y)
  gate_rmsnorm_kernel<<<dim3(BL), 256, 0, stream>>>(ybuf, zbuf, norm_w);
  // 7) out_proj: out = t @ w_out^T
  gemm_bt_256<float, false><<<dim3(4, 64), 512, 0, stream>>>(
      ybuf, 2048, w_out, 2048, out, 1024, 1024, 2048);
}

// Round 12
// 503.254 us; speedup vs baseline: 1.0439x; 1.0439x over previous
//
#include <hip/hip_runtime.h>
#include <hip/hip_bf16.h>
#include <math.h>

// ---------------------------------------------------------------------------
// Mamba2 block forward. bf16 storage + MFMA everywhere, fp32 accumulate.
// b=4, L=4096, D_MODEL=1024, D_INNER=2048, D_STATE=128, N_HEADS=32, HEAD_DIM=64
//
// Memory plan (base 234,455,040 B <= proven-safe 234.6 MB):
//   u_bf 33.5MB | xpre 76.5MB (y + sc_raw tail) | xBCc 75.5MB (z later)
//   dtT 2MB | W_all 8.98MB (W_z rows 0..2048, W_xpre rows 2048..4384)
//   out_w 4.19MB | Atot 32KB | states[0] 33.5MB | states[1] 33.5MB (OPTIONAL:
//   only if ws_size >= 268,009,472 -- runtime-checked, else 1-batch phases).
// R12: GEMM reverted to R8 2-phase BK=64 (two 8-phase attempts both ~34%
//   MfmaUtil vs R8's 37% at K=1024 -> structure loses here). S2 scan gets
//   depth-8 named-register prefetch (was 4 -> MLP-starved). SSD phases run
//   2 batches per launch when the second states buffer fits.
// ---------------------------------------------------------------------------

#define BL    16384
#define NCONV 2304
#define LDXP  2336
#define STATE_ELEMS 16777216ull   // per-batch states: 64c*32h*64p*128n bf16

typedef __hip_bfloat16 bf16;
typedef __attribute__((ext_vector_type(8))) short bf16x8_i;
typedef __attribute__((ext_vector_type(4))) float f32x4;

union BF8 { uint4 u; bf16 h[8]; };
union BF2 { uint u; bf16 h[2]; };

__device__ __forceinline__ void gload_lds16(const void* g, void* l) {
  __builtin_amdgcn_global_load_lds(
      (__attribute__((address_space(1))) void*)(uintptr_t)g,
      (__attribute__((address_space(3))) void*)(uint32_t)(uintptr_t)l,
      16, 0, 0);
}

// ---------------- bf16 MFMA GEMM (R8, proven):  C[m,n] = sum_k A[m,k]B[n,k]
// 128x128 tile, BK=64, 4 waves, double-buffered LDS + counted vmcnt,
// conflict-free swizzle: elem ^= ((row>>1)&7)<<3 (verified: conflicts = 0).
template<typename TC, bool CLAMPB>
__global__ __launch_bounds__(256) void gemm_bt_mfma(
    const bf16* __restrict__ A, int lda,
    const bf16* __restrict__ B, int ldb,
    TC* __restrict__ C, int ldc, int N, int K)
{
  __shared__ __align__(16) bf16 As2[2][128 * 64];
  __shared__ __align__(16) bf16 Bs2[2][128 * 64];
  const int tid  = threadIdx.x;
  const int lane = tid & 63;
  const int wid  = tid >> 6;

  const int gx  = gridDim.x;
  const int nwg = gx * gridDim.y;
  const int q   = nwg >> 3;
  int id = blockIdx.y * gx + blockIdx.x;
  id = (id & 7) * q + (id >> 3);
  const int bm = (id / gx) * 128;
  const int bn = (id % gx) * 128;

  const int wr = (wid >> 1) * 64;
  const int wc = (wid & 1) * 64;

  f32x4 acc[4][4] = {};

  int aoff[4][2], boff[4][2];
  #pragma unroll
  for (int i = 0; i < 4; ++i) {
    const int ar = wr + i * 16 + (lane & 15);
    const int br = wc + i * 16 + (lane & 15);
    const int asw = ((ar >> 1) & 7) << 3;
    const int bsw = ((br >> 1) & 7) << 3;
    #pragma unroll
    for (int ks = 0; ks < 2; ++ks) {
      const int c0 = ks * 32 + (lane >> 4) * 8;
      aoff[i][ks] = ar * 64 + (c0 ^ asw);
      boff[i][ks] = br * 64 + (c0 ^ bsw);
    }
  }

  const int srow = tid >> 3;
  const int sj   = tid & 7;
  const bf16* pA[4];
  const bf16* pB[4];
  #pragma unroll
  for (int i = 0; i < 4; ++i) {
    const int r  = i * 32 + srow;
    const int js = sj ^ ((r >> 1) & 7);
    int brow = bn + r;
    if (CLAMPB) brow = min(brow, N - 1);
    pA[i] = A + (size_t)(bm + r) * lda + js * 8;
    pB[i] = B + (size_t)brow * ldb + js * 8;
  }

  const int NT = K >> 6;
  #pragma unroll
  for (int i = 0; i < 4; ++i) {
    gload_lds16(pA[i], &As2[0][0] + i * 2048 + wid * 512);
    gload_lds16(pB[i], &Bs2[0][0] + i * 2048 + wid * 512);
    pA[i] += 64; pB[i] += 64;
  }

  for (int t = 0; t < NT; ++t) {
    const int cur = t & 1;
    if (t + 1 < NT) {
      bf16* dA = &As2[cur ^ 1][0];
      bf16* dB = &Bs2[cur ^ 1][0];
      #pragma unroll
      for (int i = 0; i < 4; ++i) {
        gload_lds16(pA[i], dA + i * 2048 + wid * 512);
        gload_lds16(pB[i], dB + i * 2048 + wid * 512);
        pA[i] += 64; pB[i] += 64;
      }
      asm volatile("s_waitcnt vmcnt(8)" ::: "memory");
    } else {
      asm volatile("s_waitcnt vmcnt(0)" ::: "memory");
    }
    __builtin_amdgcn_sched_barrier(0);
    __builtin_amdgcn_s_barrier();
    const bf16* Ab = &As2[cur][0];
    const bf16* Bb = &Bs2[cur][0];
    __builtin_amdgcn_s_setprio(1);
    #pragma unroll
    for (int ks = 0; ks < 2; ++ks) {
      bf16x8_i af[4], bfr[4];
      #pragma unroll
      for (int i = 0; i < 4; ++i) {
        af[i]  = *(const bf16x8_i*)(Ab + aoff[i][ks]);
        bfr[i] = *(const bf16x8_i*)(Bb + boff[i][ks]);
      }
      #pragma unroll
      for (int i = 0; i < 4; ++i)
        #pragma unroll
        for (int j = 0; j < 4; ++j)
          acc[i][j] = __builtin_amdgcn_mfma_f32_16x16x32_bf16(
              af[i], bfr[j], acc[i][j], 0, 0, 0);
    }
    __builtin_amdgcn_s_setprio(0);
    __builtin_amdgcn_s_barrier();
  }

  const int cr = (lane >> 4) * 4;
  const int cc = lane & 15;
  #pragma unroll
  for (int i = 0; i < 4; ++i) {
    #pragma unroll
    for (int j = 0; j < 4; ++j) {
      const int n = bn + wc + j * 16 + cc;
      if (n < N) {
        #pragma unroll
        for (int r = 0; r < 4; ++r) {
          const int m = bm + wr + i * 16 + cr + r;
          if constexpr (sizeof(TC) == 2)
            ((bf16*)C)[(size_t)m * ldc + n] = __float2bfloat16(acc[i][j][r]);
          else
            ((float*)C)[(size_t)m * ldc + n] = acc[i][j][r];
        }
      }
    }
  }
}

// ---------------- conversion -----------------------------------------------
__global__ __launch_bounds__(256) void cvt_f32_bf16(
    const float* __restrict__ in, bf16* __restrict__ out)
{
  const size_t i = (size_t)(blockIdx.x * 256 + threadIdx.x) * 8;
  float4 a = *(const float4*)(in + i);
  float4 b = *(const float4*)(in + i + 4);
  BF8 o;
  o.h[0] = __float2bfloat16(a.x); o.h[1] = __float2bfloat16(a.y);
  o.h[2] = __float2bfloat16(a.z); o.h[3] = __float2bfloat16(a.w);
  o.h[4] = __float2bfloat16(b.x); o.h[5] = __float2bfloat16(b.y);
  o.h[6] = __float2bfloat16(b.z); o.h[7] = __float2bfloat16(b.w);
  *(uint4*)(out + i) = o.u;
}

// ---------------- dt softplus + per-chunk Atot -----------------------------
__global__ __launch_bounds__(256) void dtsp_atot_kernel(
    const bf16* __restrict__ xpre, const float* __restrict__ dt_bias,
    const float* __restrict__ A_log,
    float* __restrict__ dtT, float* __restrict__ Atot)
{
  const int c = blockIdx.x, b = blockIdx.y;
  const int tid = threadIdx.x;
  const int h = tid & 31, lg = tid >> 5;
  __shared__ float red[8][33];
  float s = 0.f, vals[8];
  const bf16* src = xpre + ((size_t)b * 4096 + c * 64 + lg * 8) * LDXP + 2304 + h;
  const float bias = dt_bias[h];
  #pragma unroll
  for (int k = 0; k < 8; ++k) {
    float v = __bfloat162float(src[(size_t)k * LDXP]) + bias;
    v = fmaxf(v, 0.f) + log1pf(expf(-fabsf(v)));
    vals[k] = v; s += v;
  }
  float* dp = dtT + ((size_t)(b * 32 + h)) * 4096 + c * 64 + lg * 8;
  #pragma unroll
  for (int k = 0; k < 8; ++k) dp[k] = vals[k];
  red[lg][h] = s;
  __syncthreads();
  if (tid < 32) {
    float t = 0.f;
    #pragma unroll
    for (int g = 0; g < 8; ++g) t += red[g][tid];
    Atot[((size_t)b * 64 + c) * 32 + tid] = -expf(A_log[tid]) * t;
  }
}

// ---------------- depthwise causal conv(4) + bias + silu -------------------
__global__ __launch_bounds__(256) void conv_silu_kernel(
    const bf16* __restrict__ xpre,
    const float* __restrict__ conv_w,
    const float* __restrict__ conv_b,
    bf16* __restrict__ xBC)
{
  const int ch = blockIdx.x * 256 + threadIdx.x;  // < 2304
  const int t0 = blockIdx.y * 8;
  const int bb = blockIdx.z;
  const float w0 = conv_w[ch*4+0], w1 = conv_w[ch*4+1];
  const float w2 = conv_w[ch*4+2], w3 = conv_w[ch*4+3];
  const float bias = conv_b[ch];
  const size_t rb = (size_t)bb * 4096;
  const bf16* src = xpre + ch;
  float v0 = (t0 >= 3) ? __bfloat162float(src[(rb + t0 - 3) * LDXP]) : 0.f;
  float v1 = (t0 >= 2) ? __bfloat162float(src[(rb + t0 - 2) * LDXP]) : 0.f;
  float v2 = (t0 >= 1) ? __bfloat162float(src[(rb + t0 - 1) * LDXP]) : 0.f;
  for (int t = t0; t < t0 + 8; ++t) {
    float v3 = __bfloat162float(src[(rb + t) * LDXP]);
    float o = bias + w0*v0 + w1*v1 + w2*v2 + w3*v3;
    o = o / (1.f + expf(-o));
    xBC[(rb + t) * NCONV + ch] = __float2bfloat16(o);
    v0 = v1; v1 = v2; v2 = v3;
  }
}

// swizzle helper: XOR the 8-block index of l by low bits of the row
__device__ __forceinline__ int swz8(int row) { return ((row >> 3) & 7) << 3; }

// ---------------- S0: head-invariant raw scores  sc_raw = C.B^T ------------
__global__ __launch_bounds__(256) void s0_scores(
    const bf16* __restrict__ xBC, float* __restrict__ sc_raw)
{
  const int c = blockIdx.x, b = blockIdx.y;
  const int tid = threadIdx.x, lane = tid & 63, wid = tid >> 6;
  __shared__ bf16 Bc[64 * 136];
  __shared__ bf16 Cc[64 * 136];
  const size_t r0 = (size_t)b * 4096 + (size_t)c * 64;
  #pragma unroll
  for (int k = 0; k < 4; ++k) {
    int id = tid + k * 256, l = id >> 4, n0 = (id & 15) * 8;
    *(uint4*)(Bc + l * 136 + n0) =
        *(const uint4*)(xBC + (r0 + l) * NCONV + 2048 + n0);
    *(uint4*)(Cc + l * 136 + n0) =
        *(const uint4*)(xBC + (r0 + l) * NCONV + 2176 + n0);
  }
  __syncthreads();
  const int wr  = (wid & 1) * 32;   // l
  const int wcs = (wid >> 1) * 32;  // s
  f32x4 as[2][2] = {};
  #pragma unroll
  for (int ks = 0; ks < 4; ++ks) {
    const int k0 = ks * 32 + (lane >> 4) * 8;
    bf16x8_i af[2], bfr[2];
    #pragma unroll
    for (int i = 0; i < 2; ++i)
      af[i] = *(const bf16x8_i*)(Cc + (wr + i * 16 + (lane & 15)) * 136 + k0);
    #pragma unroll
    for (int j = 0; j < 2; ++j)
      bfr[j] = *(const bf16x8_i*)(Bc + (wcs + j * 16 + (lane & 15)) * 136 + k0);
    #pragma unroll
    for (int i = 0; i < 2; ++i)
      #pragma unroll
      for (int j = 0; j < 2; ++j)
        as[i][j] = __builtin_amdgcn_mfma_f32_16x16x32_bf16(
            af[i], bfr[j], as[i][j], 0, 0, 0);
  }
  float* dst = sc_raw + ((size_t)(b * 64 + c)) * 4096;
  const int cr = (lane >> 4) * 4, cc = lane & 15;
  #pragma unroll
  for (int i = 0; i < 2; ++i)
    #pragma unroll
    for (int r = 0; r < 4; ++r) {
      const int l = wr + i * 16 + cr + r;
      #pragma unroll
      for (int j = 0; j < 2; ++j)
        dst[l * 64 + wcs + j * 16 + cc] = as[i][j][r];
    }
}

// ---------------- S1: chunk-local states via MFMA --------------------------
// grid (32 h, 64 c, NB batches).
__global__ __launch_bounds__(256) void s1_localstate(
    const bf16* __restrict__ xBC, const float* __restrict__ dtT,
    const float* __restrict__ A_log, bf16* __restrict__ states, int bbase)
{
  const int hh = blockIdx.x, c = blockIdx.y;
  const int b  = bbase + blockIdx.z;
  const int tid = threadIdx.x, lane = tid & 63, wid = tid >> 6;
  __shared__ bf16 BT[128 * 72];    // [n][l^swz]
  __shared__ bf16 xwT[64 * 72];    // [p][l^swz]
  __shared__ bf16 Sout[64 * 136];  // bounce for coalesced store
  const size_t r0 = (size_t)b * 4096 + (size_t)c * 64;

  BF8 regB[4], regx[2];
  #pragma unroll
  for (int k = 0; k < 4; ++k) {
    int id = tid + k * 256, l = id >> 4, n0 = (id & 15) * 8;
    regB[k].u = *(const uint4*)(xBC + (r0 + l) * NCONV + 2048 + n0);
  }
  #pragma unroll
  for (int k = 0; k < 2; ++k) {
    int id = tid + k * 256, l = id >> 3, p0 = (id & 7) * 8;
    regx[k].u = *(const uint4*)(xBC + (r0 + l) * NCONV + hh * 64 + p0);
  }

  float d = dtT[((size_t)(b * 32 + hh)) * 4096 + c * 64 + lane];
  float Ah = -expf(A_log[hh]);
  float v = Ah * d;
  #pragma unroll
  for (int off = 1; off < 64; off <<= 1) {
    float up = __shfl_up(v, off, 64);
    if (lane >= off) v += up;
  }
  const float At = __shfl(v, 63, 64);
  const float w = d * __expf(At - v);

  #pragma unroll
  for (int k = 0; k < 4; ++k) {
    int id = tid + k * 256, l = id >> 4, n0 = (id & 15) * 8;
    #pragma unroll
    for (int j = 0; j < 8; ++j) {
      int n = n0 + j;
      BT[n * 72 + (l ^ swz8(n))] = regB[k].h[j];
    }
  }
  #pragma unroll
  for (int k = 0; k < 2; ++k) {
    int id = tid + k * 256, l = id >> 3, p0 = (id & 7) * 8;
    float wv = __shfl(w, l, 64);
    #pragma unroll
    for (int j = 0; j < 8; ++j) {
      int p = p0 + j;
      xwT[p * 72 + (l ^ swz8(p))] =
          __float2bfloat16(__bfloat162float(regx[k].h[j]) * wv);
    }
  }
  __syncthreads();

  const int wr = (wid & 1) * 32;   // p
  const int wc = (wid >> 1) * 64;  // n
  f32x4 acc[2][4] = {};
  #pragma unroll
  for (int ks = 0; ks < 2; ++ks) {
    const int k0 = ks * 32 + (lane >> 4) * 8;
    bf16x8_i a[2], bb[4];
    #pragma unroll
    for (int i = 0; i < 2; ++i) {
      int p = wr + i * 16 + (lane & 15);
      a[i] = *(const bf16x8_i*)(xwT + p * 72 + (k0 ^ swz8(p)));
    }
    #pragma unroll
    for (int j = 0; j < 4; ++j) {
      int n = wc + j * 16 + (lane & 15);
      bb[j] = *(const bf16x8_i*)(BT + n * 72 + (k0 ^ swz8(n)));
    }
    #pragma unroll
    for (int i = 0; i < 2; ++i)
      #pragma unroll
      for (int j = 0; j < 4; ++j)
        acc[i][j] = __builtin_amdgcn_mfma_f32_16x16x32_bf16(
            a[i], bb[j], acc[i][j], 0, 0, 0);
  }

  const int cr = (lane >> 4) * 4, cn = lane & 15;
  #pragma unroll
  for (int i = 0; i < 2; ++i)
    #pragma unroll
    for (int j = 0; j < 4; ++j)
      #pragma unroll
      for (int r = 0; r < 4; ++r)
        Sout[(wr + i * 16 + cr + r) * 136 + (wc + j * 16 + cn)] =
            __float2bfloat16(acc[i][j][r]);
  __syncthreads();
  bf16* sb = states + (size_t)blockIdx.z * STATE_ELEMS
                    + ((size_t)c * 32 + hh) * 8192;
  #pragma unroll
  for (int k = 0; k < 4; ++k) {
    int id = tid + k * 256, p = id >> 4, n0 = (id & 15) * 8;
    *(uint4*)(sb + p * 128 + n0) = *(const uint4*)(Sout + p * 136 + n0);
  }
}

// ---------------- S2: in-place scan over chunks (8-deep prefetch) ----------
// grid (512, NB) x 256 thr: block.x -> (h, p-quad), thread -> (p, n-pair).
#define S2STEP(R, CI)                                                     \
  {                                                                       \
    BF2 o;                                                                \
    o.h[0] = __float2bfloat16(ca); o.h[1] = __float2bfloat16(cb);         \
    const float e = ec[CI];                                               \
    ca = fmaf(e, ca, __bfloat162float(R.h[0]));                           \
    cb = fmaf(e, cb, __bfloat162float(R.h[1]));                           \
    *(uint*)(ptr + (size_t)(CI) * cs) = o.u;                              \
    if ((CI) + 8 < 64) R.u = *(const uint*)(ptr + (size_t)((CI) + 8) * cs); \
  }

__global__ __launch_bounds__(256) void s2_scan(
    bf16* __restrict__ states, const float* __restrict__ Atot, int bbase)
{
  const int h  = blockIdx.x >> 4;
  const int p  = ((blockIdx.x & 15) << 2) | (threadIdx.x >> 6);
  const int n0 = (threadIdx.x & 63) * 2;
  const int b  = bbase + blockIdx.y;
  __shared__ float ec[64];
  if (threadIdx.x < 64)
    ec[threadIdx.x] = expf(Atot[((size_t)b * 64 + threadIdx.x) * 32 + h]);
  __syncthreads();
  bf16* ptr = states + (size_t)blockIdx.y * STATE_ELEMS
                     + ((size_t)h * 64 + p) * 128 + n0;
  const size_t cs = (size_t)32 * 8192;
  float ca = 0.f, cb = 0.f;
  BF2 r0, r1, r2, r3, r4, r5, r6, r7;
  r0.u = *(const uint*)(ptr + 0 * cs);
  r1.u = *(const uint*)(ptr + 1 * cs);
  r2.u = *(const uint*)(ptr + 2 * cs);
  r3.u = *(const uint*)(ptr + 3 * cs);
  r4.u = *(const uint*)(ptr + 4 * cs);
  r5.u = *(const uint*)(ptr + 5 * cs);
  r6.u = *(const uint*)(ptr + 6 * cs);
  r7.u = *(const uint*)(ptr + 7 * cs);
  for (int g = 0; g < 8; ++g) {
    const int c0 = g * 8;
    S2STEP(r0, c0 + 0); S2STEP(r1, c0 + 1);
    S2STEP(r2, c0 + 2); S2STEP(r3, c0 + 3);
    S2STEP(r4, c0 + 4); S2STEP(r5, c0 + 5);
    S2STEP(r6, c0 + 6); S2STEP(r7, c0 + 7);
  }
}

// ---------------- S3: chunk outputs via MFMA (scores precomputed) ----------
// grid (32 h, 64 c, NB batches). Y written packed ld 2048.
__global__ __launch_bounds__(256) void s3_output(
    const bf16* __restrict__ xBC, const float* __restrict__ dtT,
    const float* __restrict__ A_log, const float* __restrict__ Dp,
    const bf16* __restrict__ states, const float* __restrict__ sc_raw,
    bf16* __restrict__ Y, int bbase)
{
  const int hh = blockIdx.x, c = blockIdx.y;
  const int b  = bbase + blockIdx.z;
  const int tid = threadIdx.x, lane = tid & 63, wid = tid >> 6;
  __shared__ bf16 Cc[64 * 136];   // [l][n]
  __shared__ bf16 Yb[64 * 136];   // output bounce
  __shared__ bf16 Sin[64 * 136];  // [p][n]
  __shared__ bf16 xT[64 * 72];    // [p][l^swz]
  __shared__ bf16 scb[64 * 72];   // [l][s] post-decay scores
  __shared__ float Ac[64], dts[64];
  const size_t r0 = (size_t)b * 4096 + (size_t)c * 64;

  if (tid < 64) {
    float d = dtT[((size_t)(b * 32 + hh)) * 4096 + c * 64 + tid];
    float Ah = -expf(A_log[hh]);
    float v = Ah * d;
    #pragma unroll
    for (int off = 1; off < 64; off <<= 1) {
      float up = __shfl_up(v, off, 64);
      if (tid >= off) v += up;
    }
    Ac[tid] = v; dts[tid] = d;
  }

  #pragma unroll
  for (int k = 0; k < 4; ++k) {
    int id = tid + k * 256, l = id >> 4, n0 = (id & 15) * 8;
    *(uint4*)(Cc + l * 136 + n0) =
        *(const uint4*)(xBC + (r0 + l) * NCONV + 2176 + n0);
  }
  const bf16* sb = states + (size_t)blockIdx.z * STATE_ELEMS
                          + ((size_t)c * 32 + hh) * 8192;
  #pragma unroll
  for (int k = 0; k < 4; ++k) {
    int id = tid + k * 256, p = id >> 4, n0 = (id & 15) * 8;
    *(uint4*)(Sin + p * 136 + n0) = *(const uint4*)(sb + p * 128 + n0);
  }
  #pragma unroll
  for (int k = 0; k < 2; ++k) {
    int id = tid + k * 256, l = id >> 3, p0 = (id & 7) * 8;
    BF8 v; v.u = *(const uint4*)(xBC + (r0 + l) * NCONV + hh * 64 + p0);
    #pragma unroll
    for (int j = 0; j < 8; ++j) {
      int p = p0 + j;
      xT[p * 72 + (l ^ swz8(p))] = v.h[j];
    }
  }
  __syncthreads();

  const int wr  = (wid & 1) * 32;   // l
  const int wcs = (wid >> 1) * 32;  // s / p
  bf16x8_i afrag[2][4];
  #pragma unroll
  for (int ks = 0; ks < 4; ++ks) {
    const int k0 = ks * 32 + (lane >> 4) * 8;
    #pragma unroll
    for (int i = 0; i < 2; ++i)
      afrag[i][ks] =
          *(const bf16x8_i*)(Cc + (wr + i * 16 + (lane & 15)) * 136 + k0);
  }
  {
    const float* scr = sc_raw + ((size_t)(b * 64 + c)) * 4096;
    #pragma unroll
    for (int k = 0; k < 4; ++k) {
      int idx = tid + k * 256;            // < 1024
      int l = idx >> 4, s0 = (idx & 15) * 4;
      float4 v = *(const float4*)(scr + l * 64 + s0);
      const float acl = Ac[l];
      float vv[4] = {v.x, v.y, v.z, v.w};
      #pragma unroll
      for (int j = 0; j < 4; ++j) {
        int s = s0 + j;
        float val = (s <= l) ? vv[j] * __expf(acl - Ac[s]) * dts[s] : 0.f;
        scb[l * 72 + s] = __float2bfloat16(val);
      }
    }
  }
  __syncthreads();

  f32x4 ay[2][2] = {};
  #pragma unroll
  for (int ks = 0; ks < 4; ++ks) {
    const int k0 = ks * 32 + (lane >> 4) * 8;
    #pragma unroll
    for (int j = 0; j < 2; ++j) {
      bf16x8_i bfr =
          *(const bf16x8_i*)(Sin + (wcs + j * 16 + (lane & 15)) * 136 + k0);
      #pragma unroll
      for (int i = 0; i < 2; ++i)
        ay[i][j] = __builtin_amdgcn_mfma_f32_16x16x32_bf16(
            afrag[i][ks], bfr, ay[i][j], 0, 0, 0);
    }
  }
  const int cr = (lane >> 4) * 4, cc = lane & 15;
  #pragma unroll
  for (int i = 0; i < 2; ++i)
    #pragma unroll
    for (int r = 0; r < 4; ++r) {
      const float dk = __expf(Ac[wr + i * 16 + cr + r]);
      #pragma unroll
      for (int j = 0; j < 2; ++j) ay[i][j][r] *= dk;
    }
  #pragma unroll
  for (int ks = 0; ks < 2; ++ks) {
    const int k0 = ks * 32 + (lane >> 4) * 8;
    bf16x8_i a2[2], b2[2];
    #pragma unroll
    for (int i = 0; i < 2; ++i)
      a2[i] = *(const bf16x8_i*)(scb + (wr + i * 16 + (lane & 15)) * 72 + k0);
    #pragma unroll
    for (int j = 0; j < 2; ++j) {
      int p = wcs + j * 16 + (lane & 15);
      b2[j] = *(const bf16x8_i*)(xT + p * 72 + (k0 ^ swz8(p)));
    }
    #pragma unroll
    for (int i = 0; i < 2; ++i)
      #pragma unroll
      for (int j = 0; j < 2; ++j)
        ay[i][j] = __builtin_amdgcn_mfma_f32_16x16x32_bf16(
            a2[i], b2[j], ay[i][j], 0, 0, 0);
  }
  const float Dh = Dp[hh];
  #pragma unroll
  for (int i = 0; i < 2; ++i)
    #pragma unroll
    for (int r = 0; r < 4; ++r) {
      const int l = wr + i * 16 + cr + r;
      #pragma unroll
      for (int j = 0; j < 2; ++j) {
        const int p = wcs + j * 16 + cc;
        float xv = __bfloat162float(xT[p * 72 + (l ^ swz8(p))]);
        Yb[l * 136 + p] = __float2bfloat16(ay[i][j][r] + Dh * xv);
      }
    }
  __syncthreads();
  #pragma unroll
  for (int k = 0; k < 2; ++k) {
    int id = tid + k * 256, l = id >> 3, p0 = (id & 7) * 8;
    *(uint4*)(Y + (r0 + l) * 2048 + hh * 64 + p0) =
        *(const uint4*)(Yb + l * 136 + p0);
  }
}

// ---------------- t = rmsnorm(y * silu(z)) * norm_w  (in place over y) -----
__global__ __launch_bounds__(256) void gate_rmsnorm_kernel(
    bf16* __restrict__ y, const bf16* __restrict__ z,
    const float* __restrict__ norm_w)
{
  const size_t row = blockIdx.x;
  const int tid = threadIdx.x;
  __shared__ float red[4];
  const bf16* zr = z + row * 2048;
  bf16* yr = y + row * 2048;
  BF8 zv, yv;
  zv.u = *(const uint4*)(zr + tid * 8);
  yv.u = *(const uint4*)(yr + tid * 8);
  float t[8];
  float local = 0.f;
  #pragma unroll
  for (int j = 0; j < 8; ++j) {
    float zz = __bfloat162float(zv.h[j]);
    float yy = __bfloat162float(yv.h[j]);
    float tv = yy * (zz / (1.f + expf(-zz)));
    t[j] = tv;
    local += tv * tv;
  }
  #pragma unroll
  for (int off = 32; off; off >>= 1) local += __shfl_down(local, off, 64);
  if ((tid & 63) == 0) red[tid >> 6] = local;
  __syncthreads();
  const float total = red[0] + red[1] + red[2] + red[3];
  const float scale = rsqrtf(total * (1.f / 2048.f) + 1e-5f);
  BF8 o;
  #pragma unroll
  for (int j = 0; j < 8; ++j)
    o.h[j] = __float2bfloat16(t[j] * scale * norm_w[tid * 8 + j]);
  *(uint4*)(yr + tid * 8) = o.u;
}

// ---------------------------------------------------------------------------
extern "C" void kernel_launch(void* const* d_in, const int* in_sizes, int n_in,
                              void* d_out, int out_size, void* d_ws, size_t ws_size,
                              hipStream_t stream) {
  (void)in_sizes; (void)n_in; (void)out_size;
  const float* u          = (const float*)d_in[0];
  const float* in_proj_w  = (const float*)d_in[1];
  const float* conv_w     = (const float*)d_in[2];
  const float* conv_b     = (const float*)d_in[3];
  const float* dt_bias    = (const float*)d_in[4];
  const float* A_log      = (const float*)d_in[5];
  const float* Dp         = (const float*)d_in[6];
  const float* norm_w     = (const float*)d_in[7];
  const float* out_proj_w = (const float*)d_in[8];
  float* out = (float*)d_out;

  char* ws = (char*)d_ws;
  bf16*  u_bf   = (bf16*)ws;                           //  33,554,432
  bf16*  xpre   = (bf16*)(ws + 33554432);              //  76,546,048
  bf16*  xBCc   = (bf16*)(ws + 110100480);             //  75,497,472
  float* dtT    = (float*)(ws + 185597952);            //   2,097,152
  bf16*  W_all  = (bf16*)(ws + 187695104);             //   8,978,432 (4384x1024)
  bf16*  W_z    = W_all;                               //   rows 0..2048
  bf16*  W_xpre = W_all + (size_t)2048 * 1024;         //   rows 2048..4384
  bf16*  out_w  = (bf16*)(ws + 196673536);             //   4,194,304
  float* Atot   = (float*)(ws + 200867840);            //      32,768
  bf16*  states = (bf16*)(ws + 200900608);             //  33.5MB (+33.5 opt)
  bf16*  ybuf   = xpre;                                // y ld 2048 (post-SSD)
  bf16*  zbuf   = xBCc;                                // z ld 2048 (post-SSD)
  float* sc_raw = (float*)(ws + 100663296);            // 4 MB in xpre tail

  // second states buffer only if it provably fits
  const int NB = (ws_size >= 268009472ull) ? 2 : 1;

  // 0) conversions (in_proj as ONE contiguous 4384x1024 cvt)
  cvt_f32_bf16<<<dim3(8192), 256, 0, stream>>>(u, u_bf);
  cvt_f32_bf16<<<dim3(2192), 256, 0, stream>>>(in_proj_w, W_all);
  cvt_f32_bf16<<<dim3(1024), 256, 0, stream>>>(out_proj_w, out_w);
  // 1) GEMM-X: xpre = u_bf @ W_xpre^T  (N=2336, clamp B rows)
  gemm_bt_mfma<bf16, true><<<dim3(19, 128), 256, 0, stream>>>(
      u_bf, 1024, W_xpre, 1024, xpre, LDXP, 2336, 1024);
  // 2) dt softplus + Atot
  dtsp_atot_kernel<<<dim3(64, 4), 256, 0, stream>>>(xpre, dt_bias, A_log,
                                                    dtT, Atot);
  // 3) conv + silu
  conv_silu_kernel<<<dim3(9, 512, 4), 256, 0, stream>>>(xpre, conv_w, conv_b,
                                                        xBCc);
  // 3b) head-invariant raw scores, all batches (xpre tail now dead)
  s0_scores<<<dim3(64, 4), 256, 0, stream>>>(xBCc, sc_raw);
  // 4) SSD, NB batches at a time
  for (int b0 = 0; b0 < 4; b0 += NB) {
    s1_localstate<<<dim3(32, 64, NB), 256, 0, stream>>>(xBCc, dtT, A_log,
                                                        states, b0);
    s2_scan<<<dim3(512, NB), 256, 0, stream>>>(states, Atot, b0);
    s3_output<<<dim3(32, 64, NB), 256, 0, stream>>>(xBCc, dtT, A_log, Dp,
                                                    states, sc_raw, ybuf, b0);
  }
  // 5) GEMM-Z: z = u_bf @ W_z^T (over dead conv buffer)
  gemm_bt_mfma<bf16, false><<<dim3(16, 128), 256, 0, stream>>>(
      u_bf, 1024, W_z, 1024, zbuf, 2048, 2048, 1024);
  // 6) gate + rmsnorm (t over y)
  gate_rmsnorm_kernel<<<dim3(BL), 256, 0, stream>>>(ybuf, zbuf, norm_w);
  // 7) out_proj: out = t @ out_w^T
  gemm_bt_mfma<float, false><<<dim3(8, 128), 256, 0, stream>>>(
      ybuf, 2048, out_w, 2048, out, 1024, 1024, 2048);
}